// Round 5
// baseline (244.466 us; speedup 1.0000x reference)
//
#include <hip/hip_runtime.h>
#include <math.h>

// B=8, L=32, H=1024, N=32
// ws layout (floats):
#define NODE_OFF   0          // 8192*32
#define CN_OFF     262144     // 8192*32 (diag rows used by chain init)
#define SPAN_OFF   524288     // 8192
#define D_OFF      532480     // 256*32
#define RBF_OFF    540672     // 32768 halfs (16384 floats): swizzled bf16 exp(rules)
#define PART_OFF   557056     // 4*262144
#define PARTS_OFF  1605632    // 4*8192

typedef short bf16x8 __attribute__((ext_vector_type(8)));
typedef float f32x16 __attribute__((ext_vector_type(16)));

__device__ inline short f2bf(float f) {
  union { float f; unsigned u; } v; v.f = f;
  unsigned r = (v.u + 0x7FFFu + ((v.u >> 16) & 1u)) >> 16;
  return (short)r;
}

// Fused front kernel, 896 blocks x 256:
//  0..511   : node split-K GEMM   512..767: posnode+D   768..895: Rbf swizzle
__global__ __launch_bounds__(256) void k_pre(
    const float* __restrict__ ph, const float* __restrict__ Wn,
    const float* __restrict__ Ws, const float* __restrict__ sh,
    const float* __restrict__ Wp, const float* __restrict__ bp,
    const float* __restrict__ pmask, const float* __restrict__ pu,
    const float* __restrict__ pum, const float* __restrict__ rs,
    const float* __restrict__ rm, float* __restrict__ part,
    float* __restrict__ partS, float* __restrict__ D,
    unsigned short* __restrict__ Rbf) {
  __shared__ float smem[12672];
  int t = threadIdx.x;
  int bid = blockIdx.x;
  if (bid >= 768) {   // ---- Rbf: frag-order bf16 of exp(masked rules) ----
    int idx = ((bid - 768) << 8) + t;        // [kst(64)][lane(64)][r(8)]
    int kst = idx >> 9, ln = (idx >> 3) & 63, r = idx & 7;
    int a = ln & 31;
    int kp = kst * 16 + ((ln >> 5) << 3) + r;   // k' = p*32+q
    float v = __expf(rs[a * 1024 + kp] + (rm[a * 1024 + kp] - 1.0f) * 1e10f);
    Rbf[idx] = (unsigned short)f2bf(v);
    return;
  }
  if (bid >= 512) {   // ---- posnode + D ----
    float* rowl = smem;
    float* partl = smem + 1024;
    float* posn = smem + 1288;
    int row = bid - 512;
#pragma unroll
    for (int k = 0; k < 4; ++k) rowl[t + 256 * k] = sh[row * 1024 + t + 256 * k];
    __syncthreads();
    int c = t & 31, seg = t >> 5;
    float pacc = 0.f;
    for (int hh = 0; hh < 128; ++hh)
      pacc += rowl[seg * 128 + hh] * Wp[(seg * 128 + hh) * 32 + c];
    partl[seg * 33 + c] = pacc;
    __syncthreads();
    if (t < 32) {
      float s = 0.f;
#pragma unroll
      for (int k = 0; k < 8; ++k) s += partl[k * 33 + t];
      posn[t] = s + bp[t] + (pmask[t] - 1.0f) * 1e10f;
    }
    __syncthreads();
    if (t < 32) {
      float mq = posn[t];
#pragma unroll
      for (int m = 16; m >= 1; m >>= 1) mq = fmaxf(mq, __shfl_xor(mq, m, 32));
      float sum = 0.f;
#pragma unroll 8
      for (int q = 0; q < 32; ++q)
        sum += __expf(pu[t * 32 + q] + (pum[t * 32 + q] - 1.0f) * 1e15f + posn[q] - mq);
      D[row * 32 + t] = mq + __logf(sum);
    }
    return;
  }
  // ---- node split-K GEMM ----
  float (*A)[132] = (float(*)[132])smem;
  float (*Wl)[32] = (float(*)[32])(smem + 8448);
  float* Wsl = smem + 12544;
  int rg = bid >> 2;
  int s = bid & 3;
  int row0 = rg * 64;
  int h0 = s * 256;
  int tr = t >> 3, tc = t & 7;
  int r0 = tr * 2;
  int c = tc * 4;
  float acc[8] = {0.f, 0.f, 0.f, 0.f, 0.f, 0.f, 0.f, 0.f};
  float sp0 = 0.f, sp1 = 0.f;
  for (int hc = 0; hc < 2; ++hc) {
    int hb = h0 + hc * 128;
#pragma unroll
    for (int k = 0; k < 32; ++k) {
      int f = t + 256 * k;
      int rr = f >> 7, hh = f & 127;
      A[rr][hh] = ph[(row0 + rr) * 1024 + hb + hh];
    }
#pragma unroll
    for (int k = 0; k < 16; ++k) {
      int f = t + 256 * k;
      int hh = f >> 5, cc = f & 31;
      Wl[hh][cc] = Wn[(hb + hh) * 32 + cc];
    }
    if (t < 128) Wsl[t] = Ws[hb + t];
    __syncthreads();
#pragma unroll 2
    for (int h = 0; h < 128; ++h) {
      float a0 = A[r0][h], a1 = A[r0 + 1][h];
      float4 w = *(const float4*)&Wl[h][c];
      acc[0] += a0 * w.x; acc[1] += a0 * w.y; acc[2] += a0 * w.z; acc[3] += a0 * w.w;
      acc[4] += a1 * w.x; acc[5] += a1 * w.y; acc[6] += a1 * w.z; acc[7] += a1 * w.w;
      if (tc == 0) { float wv = Wsl[h]; sp0 += a0 * wv; sp1 += a1 * wv; }
    }
    __syncthreads();
  }
  int row = row0 + r0;
  float* po = part + s * 262144;
  *(float4*)&po[row * 32 + c] = make_float4(acc[0], acc[1], acc[2], acc[3]);
  *(float4*)&po[(row + 1) * 32 + c] = make_float4(acc[4], acc[5], acc[6], acc[7]);
  if (tc == 0) {
    partS[s * 8192 + row] = sp0;
    partS[s * 8192 + row + 1] = sp1;
  }
}

__global__ __launch_bounds__(256) void k_node_reduce(
    const float* __restrict__ part, const float* __restrict__ partS,
    const float* __restrict__ bn, const float* __restrict__ bs,
    const float* __restrict__ D, float* __restrict__ node,
    float* __restrict__ cng, float* __restrict__ span) {
  int t = threadIdx.x;
  int row = blockIdx.x * 8 + (t >> 5);
  int c = t & 31;
  float v = bn[c];
#pragma unroll
  for (int s = 0; s < 4; ++s) v += part[s * 262144 + row * 32 + c];
  node[row * 32 + c] = v;
  int l = (row >> 5) & 31, m = row & 31;
  if (l == m)
    cng[row * 32 + c] = v + D[(row >> 5) * 32 + c] + v;   // chart_diag + node
  if (c == 0) {
    float sp = bs[0];
#pragma unroll
    for (int s = 0; s < 4; ++s) sp += partS[s * 8192 + row];
    span[row] = sp;
  }
}

// One block per batch; whole CKY chain in LDS; MFMA for S and rule-matvec.
// Dynamic LDS 121344 B:
//   cn    f32[528*33]           @ 0       (chart+node, triangular, stride 33)
//   Sbf   u16[16*1032]          @ 69696   (per-group S in bf16, stride 2064 B)
//   slots f32[4*1024]           @ 102720  (matvec k-split partials)
//   maxv  f32[528]              @ 119104
//   G     f32[32]               @ 121216
__global__ __launch_bounds__(1024, 4) void k_chain2(
    const float* __restrict__ node, const float* __restrict__ span,
    const float* __restrict__ cng, const unsigned short* __restrict__ Rbf,
    const int* __restrict__ sm, const float* __restrict__ rootm,
    float* __restrict__ out) {
  extern __shared__ char lds[];
  float* cn = (float*)lds;
  unsigned short* Sbf = (unsigned short*)(lds + 69696);
  float* slots = (float*)(lds + 102720);
  float* maxv = (float*)(lds + 119104);
  float* G = (float*)(lds + 121216);
  int t = threadIdx.x;
  int b = blockIdx.x;
  int w = t >> 6;         // wave 0..15
  int ln = t & 63;
  int rowB = b * 32;
  // ---- init: diagonal cells ----
  {
    int l = t >> 5, a = t & 31;
    float v = cng[((rowB + l) * 32 + l) * 32 + a];
    int off = l * (65 - l) / 2;       // idx(l,l)
    cn[off * 33 + a] = v;
    float m = v;
#pragma unroll
    for (int s = 16; s >= 1; s >>= 1) m = fmaxf(m, __shfl_xor(m, s, 32));
    if (a == 0) maxv[off] = m;
  }
  __syncthreads();
  for (int i = 1; i < 32; ++i) {
    int nT = 32 - i;
    // ---- P1: G[c] = max_j(maxv[left]+maxv[right]) ----
    {
      int c = t >> 5, j = t & 31;
      if (c < nT) {
        float g = -3.0e38f;
        if (j < i) {
          int offc = c * (65 - c) / 2;
          int m2 = c + j + 1;
          g = maxv[offc + j] + maxv[m2 * (65 - m2) / 2 + (c + i - m2)];
        }
#pragma unroll
        for (int s = 16; s >= 1; s >>= 1) g = fmaxf(g, __shfl_xor(g, s, 32));
        if (j == 0) G[c] = g;
      }
    }
    __syncthreads();
    int nG = (nT + 15) >> 4;
    for (int g = 0; g < nG; ++g) {
      // output-map prefetch: thread t owns (a_o, c_o) of the final C layout
      int a_o = (w & 3) + ((w >> 2) << 3) + ((ln >> 5) << 2);
      int c_o = ln & 31;
      int cellg = g * 16 + (c_o & 15);
      bool ovalid = (c_o < 16) && (cellg < nT);
      float node_v = 0.f, span_v = 0.f;
      if (ovalid) {
        node_v = node[((rowB + cellg) * 32 + (cellg + i)) * 32 + a_o];
        span_v = span[(rowB + cellg) * 32 + (cellg + i)];
      }
      // ---- P2: one wave per cell builds EL/ER frags + S-MFMA ----
      int cg = g * 16 + w;
      if (cg < nT) {
        int t0 = cg, e = cg + i;
        int pq = ln & 31;
        int jb = (ln >> 5) << 3;
        float Gc = G[cg];
        int offt0 = t0 * (65 - t0) / 2;
        f32x16 Sacc = {};
        bf16x8 af, bfr;
#pragma unroll
        for (int r = 0; r < 8; ++r) {
          int j = jb + r;
          float elv = 0.f, erv = 0.f;
          if (j < i) {
            int m2 = t0 + j + 1;
            int rcell = m2 * (65 - m2) / 2 + (e - m2);
            float bet = maxv[rcell];
            elv = __expf(cn[(offt0 + j) * 33 + pq] + bet - Gc);
            erv = __expf(cn[rcell * 33 + pq] - bet);
          }
          af[r] = f2bf(elv);
          bfr[r] = f2bf(erv);
        }
        Sacc = __builtin_amdgcn_mfma_f32_32x32x16_bf16(af, bfr, Sacc, 0, 0, 0);
        if (i > 16) {
#pragma unroll
          for (int r = 0; r < 8; ++r) {
            int j = 16 + jb + r;
            float elv = 0.f, erv = 0.f;
            if (j < i) {
              int m2 = t0 + j + 1;
              int rcell = m2 * (65 - m2) / 2 + (e - m2);
              float bet = maxv[rcell];
              elv = __expf(cn[(offt0 + j) * 33 + pq] + bet - Gc);
              erv = __expf(cn[rcell * 33 + pq] - bet);
            }
            af[r] = f2bf(elv);
            bfr[r] = f2bf(erv);
          }
          Sacc = __builtin_amdgcn_mfma_f32_32x32x16_bf16(af, bfr, Sacc, 0, 0, 0);
        }
        // write S (bf16) to slot w; C/D layout: col=lane&31, row=(reg&3)+8*(reg>>2)+4*(lane>>5)
        unsigned short* sb = Sbf + w * 1032;
        int q = ln & 31, hi = (ln >> 5) << 2;
#pragma unroll
        for (int rr = 0; rr < 16; ++rr) {
          int p = (rr & 3) + ((rr >> 2) << 3) + hi;
          sb[p * 32 + q] = (unsigned short)f2bf(Sacc[rr]);
        }
      }
      __syncthreads();
      // ---- P3: rule matvec, waves 0..3, k' split 256 each ----
      if (w < 4) {
        f32x16 C = {};
#pragma unroll
        for (int tt = 0; tt < 16; ++tt) {
          int kst = (w << 4) + tt;
          bf16x8 ra = *(const bf16x8*)(Rbf + (kst << 9) + (ln << 3));
          bf16x8 sbv = *(const bf16x8*)(Sbf + (ln & 15) * 1032 + (kst << 4) + ((ln >> 5) << 3));
          C = __builtin_amdgcn_mfma_f32_32x32x16_bf16(ra, sbv, C, 0, 0, 0);
        }
        float* sl = slots + (w << 10);
#pragma unroll
        for (int rr = 0; rr < 16; ++rr) sl[(rr << 6) + ln] = C[rr];
      }
      __syncthreads();
      // ---- fused k-sum + output (thread (w=reg, ln)) ----
      {
        float pt = slots[(w << 6) + ln] + slots[1024 + (w << 6) + ln] +
                   slots[2048 + (w << 6) + ln] + slots[3072 + (w << 6) + ln];
        if (ovalid) {
          float v = G[cellg] + __logf(pt) + node_v + span_v;  // chart value
          cn[(cellg * (65 - cellg) / 2 + i) * 33 + a_o] = v + node_v;
        }
      }
      __syncthreads();
    }
    // ---- maxv for the new diagonal of cells ----
    {
      int c = t >> 5, a = t & 31;
      if (c < nT) {
        int ix = c * (65 - c) / 2 + i;
        float m = cn[ix * 33 + a];
#pragma unroll
        for (int s = 16; s >= 1; s >>= 1) m = fmaxf(m, __shfl_xor(m, s, 32));
        if (a == 0) maxv[ix] = m;
      }
    }
    __syncthreads();
  }
  // ---- logits ----
  if (t < 32) {
    int len = 0;
#pragma unroll
    for (int l = 0; l < 32; ++l) len += sm[b * 32 + l];
    int e = len - 1;
    float cv = cn[e * 33 + t] - node[((rowB)*32 + e) * 32 + t];  // idx(0,e)=e
    out[b * 32 + t] = cv + (rootm[t] - 1.0f) * 1e10f;
  }
}

extern "C" void kernel_launch(void* const* d_in, const int* in_sizes, int n_in,
                              void* d_out, int out_size, void* d_ws, size_t ws_size,
                              hipStream_t stream) {
  const float* ph    = (const float*)d_in[0];
  const float* sh    = (const float*)d_in[1];
  const int*   sm    = (const int*)  d_in[2];
  const float* Wp    = (const float*)d_in[3];
  const float* bp    = (const float*)d_in[4];
  const float* Wn    = (const float*)d_in[5];
  const float* bn    = (const float*)d_in[6];
  const float* Ws    = (const float*)d_in[7];
  const float* bs    = (const float*)d_in[8];
  const float* rs    = (const float*)d_in[9];
  const float* pu    = (const float*)d_in[10];
  const float* rootm = (const float*)d_in[11];
  const float* pm    = (const float*)d_in[12];
  const float* rm    = (const float*)d_in[13];
  const float* pum   = (const float*)d_in[14];
  float* out = (float*)d_out;

  float* ws    = (float*)d_ws;
  float* node  = ws + NODE_OFF;
  float* cng   = ws + CN_OFF;
  float* span  = ws + SPAN_OFF;
  float* D     = ws + D_OFF;
  unsigned short* Rbf = (unsigned short*)(ws + RBF_OFF);
  float* part  = ws + PART_OFF;
  float* partS = ws + PARTS_OFF;

  hipFuncSetAttribute((const void*)k_chain2,
                      hipFuncAttributeMaxDynamicSharedMemorySize, 121344);
  k_pre<<<896, 256, 0, stream>>>(ph, Wn, Ws, sh, Wp, bp, pm, pu, pum, rs, rm,
                                 part, partS, D, Rbf);
  k_node_reduce<<<1024, 256, 0, stream>>>(part, partS, bn, bs, D, node, cng, span);
  k_chain2<<<8, 1024, 121344, stream>>>(node, span, cng, Rbf, sm, rootm, out);
}